// Round 2
// baseline (1009.762 us; speedup 1.0000x reference)
//
#include <hip/hip_runtime.h>
#include <math.h>

#define NEXP 8
#define DIN 128
#define ISZ 16
#define TT 8                       // tokens per wave
#define NWAVE 4
#define TOK_PER_BLK (TT * NWAVE)   // 32
#define NTOK (16 * 4096)           // 65536

#define LDS_GY (TOK_PER_BLK * DIN) // 4096 floats = 16 KB
#define SMEM_BYTES (LDS_GY * 4)

// ---- pack w1 [e][c][i] into lane-major P: ----
// P[c4*512 + lane*8 + m*4 + k] = w1[e][4*c4+k][2*g+m],  lane = e*8+g
// so in GEMM1, lane (e,g) loads its 8 weights for c-chunk c4 as two
// contiguous float4s at P + c4*512 + lane*8 (the wave covers 2 KB contiguous).
__global__ void pack_w1_kernel(const float* __restrict__ w1, float* __restrict__ P) {
    int idx = blockIdx.x * 256 + threadIdx.x;       // 0 .. 16383
    int c4 = idx >> 9;
    int r  = idx & 511;
    int ln = r >> 3;
    int j  = r & 7;
    int m  = j >> 2;
    int k  = j & 3;
    int e  = ln >> 3;
    int g  = ln & 7;
    P[idx] = w1[e * 2048 + (4 * c4 + k) * 16 + (2 * g + m)];
}

__global__ __launch_bounds__(256, 6) void moe_fused_kernel(
    const float* __restrict__ x,
    const float* __restrict__ rw,
    const float* __restrict__ P,     // packed w1 in d_ws
    const float* __restrict__ w2,
    float* __restrict__ out_agg,
    float* __restrict__ out_exp)
{
    extern __shared__ float lds[];
    float* gys = lds;                        // [32 tok][128]  gelu(y) handoff

    const int tid  = threadIdx.x;
    const int wave = tid >> 6;
    const int lane = tid & 63;
    const int btok = blockIdx.x * TOK_PER_BLK;
    const int wtok = btok + wave * TT;       // this wave's first token

    float* gyw = gys + wave * TT * DIN;      // wave-private gy slice

    // ================= GEMM1: y[t][e][i] = x . w1 =================
    // lane -> (e = lane>>3, g = lane&7); computes i = 2g, 2g+1 for 8 tokens
    const int e1 = lane >> 3;
    const int g  = lane & 7;

    float y0[TT], y1[TT];
#pragma unroll
    for (int t = 0; t < TT; ++t) { y0[t] = 0.f; y1[t] = 0.f; }

    const float* xg = x + (size_t)wtok * DIN;     // wave-uniform base
    const float* Pl = P + lane * 8;

#pragma unroll 4
    for (int c4 = 0; c4 < DIN / 4; ++c4) {
        float4 wa = *(const float4*)(Pl + c4 * 512);
        float4 wb = *(const float4*)(Pl + c4 * 512 + 4);
#pragma unroll
        for (int t = 0; t < TT; ++t) {
            float4 xv = *(const float4*)(xg + t * DIN + c4 * 4);  // uniform addr
            y0[t] += xv.x * wa.x + xv.y * wa.y + xv.z * wa.z + xv.w * wa.w;
            y1[t] += xv.x * wb.x + xv.y * wb.y + xv.z * wb.z + xv.w * wb.w;
        }
    }

    // ---- exact GELU, write to LDS handoff ----
#pragma unroll
    for (int t = 0; t < TT; ++t) {
        float a = y0[t], b = y1[t];
        a = 0.5f * a * (1.f + erff(a * 0.70710678118654752f));
        b = 0.5f * b * (1.f + erff(b * 0.70710678118654752f));
        *(float2*)(gyw + t * DIN + e1 * ISZ + 2 * g) = make_float2(a, b);
    }
    __syncthreads();

    // ================= GEMM2 + weighted agg =================
    // lane -> c4 = lane&31 (channel quad), h = lane>>5 (expert parity)
    const int c4 = lane & 31;
    const int h  = lane >> 5;

#pragma unroll
    for (int th = 0; th < 2; ++th) {          // two 4-token halves (reg pressure)
        float agg[4][4];
#pragma unroll
        for (int t = 0; t < 4; ++t) {
            agg[t][0] = 0.f; agg[t][1] = 0.f; agg[t][2] = 0.f; agg[t][3] = 0.f;
        }

#pragma unroll
        for (int k = 0; k < 4; ++k) {
            const int e = 2 * k + h;
            const float* w2e = w2 + e * (ISZ * DIN) + c4 * 4;
            float acc[4][4];
#pragma unroll
            for (int t = 0; t < 4; ++t) {
                acc[t][0] = 0.f; acc[t][1] = 0.f; acc[t][2] = 0.f; acc[t][3] = 0.f;
            }
#pragma unroll
            for (int i4 = 0; i4 < 4; ++i4) {
                float4 wv0 = *(const float4*)(w2e + (i4 * 4 + 0) * DIN);
                float4 wv1 = *(const float4*)(w2e + (i4 * 4 + 1) * DIN);
                float4 wv2 = *(const float4*)(w2e + (i4 * 4 + 2) * DIN);
                float4 wv3 = *(const float4*)(w2e + (i4 * 4 + 3) * DIN);
#pragma unroll
                for (int t = 0; t < 4; ++t) {
                    const int tt = th * 4 + t;
                    float4 gv = *(const float4*)(gyw + tt * DIN + e * ISZ + i4 * 4);
                    acc[t][0] += gv.x * wv0.x + gv.y * wv1.x + gv.z * wv2.x + gv.w * wv3.x;
                    acc[t][1] += gv.x * wv0.y + gv.y * wv1.y + gv.z * wv2.y + gv.w * wv3.y;
                    acc[t][2] += gv.x * wv0.z + gv.y * wv1.z + gv.z * wv2.z + gv.w * wv3.z;
                    acc[t][3] += gv.x * wv0.w + gv.y * wv1.w + gv.z * wv2.w + gv.w * wv3.w;
                }
            }
#pragma unroll
            for (int t = 0; t < 4; ++t) {
                const int gtok = wtok + th * 4 + t;
                *(float4*)(out_exp + (size_t)gtok * (NEXP * DIN) + e * DIN + c4 * 4) =
                    make_float4(acc[t][0], acc[t][1], acc[t][2], acc[t][3]);
                float r = rw[(size_t)gtok * NEXP + e];
                agg[t][0] += r * acc[t][0];
                agg[t][1] += r * acc[t][1];
                agg[t][2] += r * acc[t][2];
                agg[t][3] += r * acc[t][3];
            }
        }

        // combine expert parities: lane l (+) lane l^32, then lanes 0..31 write
#pragma unroll
        for (int t = 0; t < 4; ++t) {
#pragma unroll
            for (int j = 0; j < 4; ++j)
                agg[t][j] += __shfl_xor(agg[t][j], 32);
        }
        if (h == 0) {
#pragma unroll
            for (int t = 0; t < 4; ++t) {
                const int gtok = wtok + th * 4 + t;
                *(float4*)(out_agg + (size_t)gtok * DIN + c4 * 4) =
                    make_float4(agg[t][0], agg[t][1], agg[t][2], agg[t][3]);
            }
        }
    }
}

extern "C" void kernel_launch(void* const* d_in, const int* in_sizes, int n_in,
                              void* d_out, int out_size, void* d_ws, size_t ws_size,
                              hipStream_t stream) {
    const float* x  = (const float*)d_in[0];
    const float* rw = (const float*)d_in[1];
    const float* w1 = (const float*)d_in[2];
    const float* w2 = (const float*)d_in[3];

    float* out_agg = (float*)d_out;                  // [NTOK][128]
    float* out_exp = out_agg + (size_t)NTOK * DIN;   // [NTOK][8][128]
    float* P = (float*)d_ws;                         // 64 KB packed w1

    pack_w1_kernel<<<dim3(64), dim3(256), 0, stream>>>(w1, P);

    dim3 grid(NTOK / TOK_PER_BLK);   // 2048
    dim3 block(256);
    moe_fused_kernel<<<grid, block, SMEM_BYTES, stream>>>(
        x, rw, P, w2, out_agg, out_exp);
}

// Round 3
// 790.870 us; speedup vs baseline: 1.2768x; 1.2768x over previous
//
#include <hip/hip_runtime.h>
#include <math.h>

#define NEXP 8
#define DIN 128
#define ISZ 16
#define TT 16                      // tokens per wave
#define NWAVE 4
#define TOK_PER_BLK (TT * NWAVE)   // 64
#define NTOK (16 * 4096)           // 65536

#define LDS_GY (TOK_PER_BLK * DIN) // 8192 floats = 32 KB
#define SMEM_BYTES (LDS_GY * 4)

// ---- pack w1 [e][c][i] into lane-major P: ----
// P[c4*512 + lane*8 + m*4 + k] = w1[e][4*c4+k][2*g+m],  lane = e*8+g
// GEMM1: lane (e,g) loads its 8 weights for c-chunk c4 as two contiguous
// float4s at P + c4*512 + lane*8 (each wave instruction covers 2 KB contiguous).
__global__ void pack_w1_kernel(const float* __restrict__ w1, float* __restrict__ P) {
    int idx = blockIdx.x * 256 + threadIdx.x;       // 0 .. 16383
    int c4 = idx >> 9;
    int r  = idx & 511;
    int ln = r >> 3;
    int j  = r & 7;
    int m  = j >> 2;
    int k  = j & 3;
    int e  = ln >> 3;
    int g  = ln & 7;
    P[idx] = w1[e * 2048 + (4 * c4 + k) * 16 + (2 * g + m)];
}

__global__ __launch_bounds__(256, 4) void moe_fused_kernel(
    const float* __restrict__ x,
    const float* __restrict__ rw,
    const float* __restrict__ P,     // packed w1 in d_ws
    const float* __restrict__ w2,
    float* __restrict__ out_agg,
    float* __restrict__ out_exp)
{
    extern __shared__ float lds[];
    float* gys = lds;                        // [64 tok][128]  gelu(y) handoff

    const int tid  = threadIdx.x;
    const int wave = tid >> 6;
    const int lane = tid & 63;
    const int btok = blockIdx.x * TOK_PER_BLK;
    const int wtok = btok + wave * TT;       // this wave's first token

    float* gyw = gys + wave * TT * DIN;      // wave-private gy slice (8 KB)

    // ================= GEMM1: y[t][e][i] = x . w1 =================
    // lane -> (e = lane>>3, g = lane&7); computes i = 2g, 2g+1 for 16 tokens
    const int e1 = lane >> 3;
    const int g  = lane & 7;

    float y0[TT], y1[TT];
#pragma unroll
    for (int t = 0; t < TT; ++t) { y0[t] = 0.f; y1[t] = 0.f; }

    const float* xg = x + (size_t)wtok * DIN;     // wave-uniform base
    const float* Pl = P + lane * 8;

#pragma unroll 4
    for (int c4 = 0; c4 < DIN / 4; ++c4) {
        float4 wa = *(const float4*)(Pl + c4 * 512);
        float4 wb = *(const float4*)(Pl + c4 * 512 + 4);
#pragma unroll
        for (int t = 0; t < TT; ++t) {
            float4 xv = *(const float4*)(xg + t * DIN + c4 * 4);  // uniform addr
            y0[t] += xv.x * wa.x + xv.y * wa.y + xv.z * wa.z + xv.w * wa.w;
            y1[t] += xv.x * wb.x + xv.y * wb.y + xv.z * wb.z + xv.w * wb.w;
        }
    }

    // ---- exact GELU, write to LDS handoff ----
#pragma unroll
    for (int t = 0; t < TT; ++t) {
        float a = y0[t], b = y1[t];
        a = 0.5f * a * (1.f + erff(a * 0.70710678118654752f));
        b = 0.5f * b * (1.f + erff(b * 0.70710678118654752f));
        *(float2*)(gyw + t * DIN + e1 * ISZ + 2 * g) = make_float2(a, b);
    }
    __syncthreads();

    // ================= GEMM2 + weighted agg =================
    // lane -> c4 = lane&31 (channel quad), h = lane>>5 (expert parity)
    const int c4 = lane & 31;
    const int h  = lane >> 5;

#pragma unroll
    for (int th = 0; th < 2; ++th) {          // two 8-token halves (reg pressure)
        float agg[8][4];
#pragma unroll
        for (int t = 0; t < 8; ++t) {
            agg[t][0] = 0.f; agg[t][1] = 0.f; agg[t][2] = 0.f; agg[t][3] = 0.f;
        }

#pragma unroll
        for (int k = 0; k < 4; ++k) {
            const int e = 2 * k + h;
            const float* w2e = w2 + e * (ISZ * DIN) + c4 * 4;
            float acc[8][4];
#pragma unroll
            for (int t = 0; t < 8; ++t) {
                acc[t][0] = 0.f; acc[t][1] = 0.f; acc[t][2] = 0.f; acc[t][3] = 0.f;
            }
#pragma unroll
            for (int i4 = 0; i4 < 4; ++i4) {
                float4 wv0 = *(const float4*)(w2e + (i4 * 4 + 0) * DIN);
                float4 wv1 = *(const float4*)(w2e + (i4 * 4 + 1) * DIN);
                float4 wv2 = *(const float4*)(w2e + (i4 * 4 + 2) * DIN);
                float4 wv3 = *(const float4*)(w2e + (i4 * 4 + 3) * DIN);
#pragma unroll
                for (int t = 0; t < 8; ++t) {
                    const int tt = th * 8 + t;
                    // broadcast LDS read (address depends only on h)
                    float4 gv = *(const float4*)(gyw + tt * DIN + e * ISZ + i4 * 4);
                    acc[t][0] += gv.x * wv0.x + gv.y * wv1.x + gv.z * wv2.x + gv.w * wv3.x;
                    acc[t][1] += gv.x * wv0.y + gv.y * wv1.y + gv.z * wv2.y + gv.w * wv3.y;
                    acc[t][2] += gv.x * wv0.z + gv.y * wv1.z + gv.z * wv2.z + gv.w * wv3.z;
                    acc[t][3] += gv.x * wv0.w + gv.y * wv1.w + gv.z * wv2.w + gv.w * wv3.w;
                }
            }
#pragma unroll
            for (int t = 0; t < 8; ++t) {
                const int gtok = wtok + th * 8 + t;
                *(float4*)(out_exp + (size_t)gtok * (NEXP * DIN) + e * DIN + c4 * 4) =
                    make_float4(acc[t][0], acc[t][1], acc[t][2], acc[t][3]);
                float r = rw[(size_t)gtok * NEXP + e];
                agg[t][0] += r * acc[t][0];
                agg[t][1] += r * acc[t][1];
                agg[t][2] += r * acc[t][2];
                agg[t][3] += r * acc[t][3];
            }
        }

        // combine expert parities: lane l (+) lane l^32, then lanes 0..31 write
#pragma unroll
        for (int t = 0; t < 8; ++t) {
#pragma unroll
            for (int j = 0; j < 4; ++j)
                agg[t][j] += __shfl_xor(agg[t][j], 32);
        }
        if (h == 0) {
#pragma unroll
            for (int t = 0; t < 8; ++t) {
                const int gtok = wtok + th * 8 + t;
                *(float4*)(out_agg + (size_t)gtok * DIN + c4 * 4) =
                    make_float4(agg[t][0], agg[t][1], agg[t][2], agg[t][3]);
            }
        }
    }
}

extern "C" void kernel_launch(void* const* d_in, const int* in_sizes, int n_in,
                              void* d_out, int out_size, void* d_ws, size_t ws_size,
                              hipStream_t stream) {
    const float* x  = (const float*)d_in[0];
    const float* rw = (const float*)d_in[1];
    const float* w1 = (const float*)d_in[2];
    const float* w2 = (const float*)d_in[3];

    float* out_agg = (float*)d_out;                  // [NTOK][128]
    float* out_exp = out_agg + (size_t)NTOK * DIN;   // [NTOK][8][128]
    float* P = (float*)d_ws;                         // 64 KB packed w1

    pack_w1_kernel<<<dim3(64), dim3(256), 0, stream>>>(w1, P);

    dim3 grid(NTOK / TOK_PER_BLK);   // 1024
    dim3 block(256);
    moe_fused_kernel<<<grid, block, SMEM_BYTES, stream>>>(
        x, rw, P, w2, out_agg, out_exp);
}

// Round 5
// 510.798 us; speedup vs baseline: 1.9768x; 1.5483x over previous
//
#include <hip/hip_runtime.h>
#include <math.h>

#define NEXP 8
#define DIN 128
#define ISZ 16
#define TT 16                      // tokens per wave
#define NWAVE 4
#define TOK_PER_BLK (TT * NWAVE)   // 64
#define NTOK (16 * 4096)           // 65536

#define LDS_GY (TOK_PER_BLK * DIN) // 8192 floats = 32 KB
#define SMEM_BYTES (LDS_GY * 4)

typedef float f32x4 __attribute__((ext_vector_type(4)));

// ---- pack w1 [e][c][i] into lane-major P: ----
// P[c4*512 + lane*8 + m*4 + k] = w1[e][4*c4+k][2*g+m],  lane = e*8+g
// GEMM1: lane (e,g) loads its 8 weights for c-chunk c4 as two contiguous
// float4s at P + c4*512 + lane*8 (each wave instruction covers 2 KB contiguous).
__global__ void pack_w1_kernel(const float* __restrict__ w1, float* __restrict__ P) {
    int idx = blockIdx.x * 256 + threadIdx.x;       // 0 .. 16383
    int c4 = idx >> 9;
    int r  = idx & 511;
    int ln = r >> 3;
    int j  = r & 7;
    int m  = j >> 2;
    int k  = j & 3;
    int e  = ln >> 3;
    int g  = ln & 7;
    P[idx] = w1[e * 2048 + (4 * c4 + k) * 16 + (2 * g + m)];
}

__global__ __launch_bounds__(256, 1) void moe_fused_kernel(
    const float* __restrict__ x,
    const float* __restrict__ rw,
    const float* __restrict__ P,     // packed w1 in d_ws
    const float* __restrict__ w2,
    float* __restrict__ out_agg,
    float* __restrict__ out_exp)
{
    extern __shared__ float lds[];
    float* gys = lds;                        // [64 tok][128]  gelu(y) handoff

    const int tid  = threadIdx.x;
    const int wave = tid >> 6;
    const int lane = tid & 63;
    const int btok = blockIdx.x * TOK_PER_BLK;
    const int wtok = btok + wave * TT;       // this wave's first token

    float* gyw = gys + wave * TT * DIN;      // wave-private gy slice (8 KB)

    // ================= GEMM1: y[t][e][i] = x . w1 =================
    // lane -> (e = lane>>3, g = lane&7); computes i = 2g, 2g+1 for 16 tokens
    const int e1 = lane >> 3;
    const int g  = lane & 7;

    float y0[TT], y1[TT];
#pragma unroll
    for (int t = 0; t < TT; ++t) { y0[t] = 0.f; y1[t] = 0.f; }

    const float* xg = x + (size_t)wtok * DIN;     // wave-uniform base
    const float* Pl = P + lane * 8;

#pragma unroll 4
    for (int c4 = 0; c4 < DIN / 4; ++c4) {
        f32x4 wa = *(const f32x4*)(Pl + c4 * 512);
        f32x4 wb = *(const f32x4*)(Pl + c4 * 512 + 4);
#pragma unroll
        for (int t = 0; t < TT; ++t) {
            f32x4 xv = __builtin_nontemporal_load(
                (const f32x4*)(xg + t * DIN + c4 * 4));   // uniform addr, stream
            y0[t] += xv.x * wa.x + xv.y * wa.y + xv.z * wa.z + xv.w * wa.w;
            y1[t] += xv.x * wb.x + xv.y * wb.y + xv.z * wb.z + xv.w * wb.w;
        }
    }

    // ---- exact GELU, write to LDS handoff ----
#pragma unroll
    for (int t = 0; t < TT; ++t) {
        float a = y0[t], b = y1[t];
        a = 0.5f * a * (1.f + erff(a * 0.70710678118654752f));
        b = 0.5f * b * (1.f + erff(b * 0.70710678118654752f));
        *(float2*)(gyw + t * DIN + e1 * ISZ + 2 * g) = make_float2(a, b);
    }
    __syncthreads();

    // ================= GEMM2 + weighted agg =================
    // lane -> c4 = lane&31 (channel quad), h = lane>>5 (expert parity)
    const int c4 = lane & 31;
    const int h  = lane >> 5;

#pragma unroll
    for (int th = 0; th < 2; ++th) {          // two 8-token halves (reg pressure)
        float agg[8][4];
#pragma unroll
        for (int t = 0; t < 8; ++t) {
            agg[t][0] = 0.f; agg[t][1] = 0.f; agg[t][2] = 0.f; agg[t][3] = 0.f;
        }

#pragma unroll
        for (int k = 0; k < 4; ++k) {
            const int e = 2 * k + h;
            const float* w2e = w2 + e * (ISZ * DIN) + c4 * 4;
            float acc[8][4];
#pragma unroll
            for (int t = 0; t < 8; ++t) {
                acc[t][0] = 0.f; acc[t][1] = 0.f; acc[t][2] = 0.f; acc[t][3] = 0.f;
            }
#pragma unroll
            for (int i4 = 0; i4 < 4; ++i4) {
                f32x4 wv0 = *(const f32x4*)(w2e + (i4 * 4 + 0) * DIN);
                f32x4 wv1 = *(const f32x4*)(w2e + (i4 * 4 + 1) * DIN);
                f32x4 wv2 = *(const f32x4*)(w2e + (i4 * 4 + 2) * DIN);
                f32x4 wv3 = *(const f32x4*)(w2e + (i4 * 4 + 3) * DIN);
#pragma unroll
                for (int t = 0; t < 8; ++t) {
                    const int tt = th * 8 + t;
                    // broadcast LDS read (address depends only on h)
                    f32x4 gv = *(const f32x4*)(gyw + tt * DIN + e * ISZ + i4 * 4);
                    acc[t][0] += gv.x * wv0.x + gv.y * wv1.x + gv.z * wv2.x + gv.w * wv3.x;
                    acc[t][1] += gv.x * wv0.y + gv.y * wv1.y + gv.z * wv2.y + gv.w * wv3.y;
                    acc[t][2] += gv.x * wv0.z + gv.y * wv1.z + gv.z * wv2.z + gv.w * wv3.z;
                    acc[t][3] += gv.x * wv0.w + gv.y * wv1.w + gv.z * wv2.w + gv.w * wv3.w;
                }
            }
#pragma unroll
            for (int t = 0; t < 8; ++t) {
                const int gtok = wtok + th * 8 + t;
                f32x4 v = {acc[t][0], acc[t][1], acc[t][2], acc[t][3]};
                __builtin_nontemporal_store(v,
                    (f32x4*)(out_exp + (size_t)gtok * (NEXP * DIN) + e * DIN + c4 * 4));
                float r = rw[(size_t)gtok * NEXP + e];
                agg[t][0] += r * acc[t][0];
                agg[t][1] += r * acc[t][1];
                agg[t][2] += r * acc[t][2];
                agg[t][3] += r * acc[t][3];
            }
        }

        // combine expert parities: lane l (+) lane l^32, then lanes 0..31 write
#pragma unroll
        for (int t = 0; t < 8; ++t) {
#pragma unroll
            for (int j = 0; j < 4; ++j)
                agg[t][j] += __shfl_xor(agg[t][j], 32);
        }
        if (h == 0) {
#pragma unroll
            for (int t = 0; t < 8; ++t) {
                const int gtok = wtok + th * 8 + t;
                f32x4 v = {agg[t][0], agg[t][1], agg[t][2], agg[t][3]};
                __builtin_nontemporal_store(v,
                    (f32x4*)(out_agg + (size_t)gtok * DIN + c4 * 4));
            }
        }
    }
}

extern "C" void kernel_launch(void* const* d_in, const int* in_sizes, int n_in,
                              void* d_out, int out_size, void* d_ws, size_t ws_size,
                              hipStream_t stream) {
    const float* x  = (const float*)d_in[0];
    const float* rw = (const float*)d_in[1];
    const float* w1 = (const float*)d_in[2];
    const float* w2 = (const float*)d_in[3];

    float* out_agg = (float*)d_out;                  // [NTOK][128]
    float* out_exp = out_agg + (size_t)NTOK * DIN;   // [NTOK][8][128]
    float* P = (float*)d_ws;                         // 64 KB packed w1

    pack_w1_kernel<<<dim3(64), dim3(256), 0, stream>>>(w1, P);

    dim3 grid(NTOK / TOK_PER_BLK);   // 1024
    dim3 block(256);
    moe_fused_kernel<<<grid, block, SMEM_BYTES, stream>>>(
        x, rw, P, w2, out_agg, out_exp);
}

// Round 6
// 215.946 us; speedup vs baseline: 4.6760x; 2.3654x over previous
//
#include <hip/hip_runtime.h>
#include <math.h>

#define NEXP 8
#define DIN 128
#define ISZ 16
#define TT 8                       // tokens per wave (occupancy-friendly)
#define NWAVE 4
#define TOK_PER_BLK (TT * NWAVE)   // 32
#define NTOK (16 * 4096)           // 65536

#define LDS_GY (TOK_PER_BLK * DIN) // 4096 floats = 16 KB
#define SMEM_BYTES (LDS_GY * 4)

typedef float f32x4 __attribute__((ext_vector_type(4)));

// ---- pack w1 [e][c][i] into lane-major P: ----
// P[c4*512 + lane*8 + m*4 + k] = w1[e][4*c4+k][2*g+m],  lane = e*8+g
// GEMM1: lane (e,g) loads its 8 weights for c-chunk c4 as two contiguous
// float4s at P + c4*512 + lane*8 (each wave instruction covers 2 KB contiguous).
__global__ void pack_w1_kernel(const float* __restrict__ w1, float* __restrict__ P) {
    int idx = blockIdx.x * 256 + threadIdx.x;       // 0 .. 16383
    int c4 = idx >> 9;
    int r  = idx & 511;
    int ln = r >> 3;
    int j  = r & 7;
    int m  = j >> 2;
    int k  = j & 3;
    int e  = ln >> 3;
    int g  = ln & 7;
    P[idx] = w1[e * 2048 + (4 * c4 + k) * 16 + (2 * g + m)];
}

__global__ __launch_bounds__(256, 1) void moe_fused_kernel(
    const float* __restrict__ x,
    const float* __restrict__ rw,
    const float* __restrict__ P,     // packed w1 in d_ws
    const float* __restrict__ w2,
    float* __restrict__ out_agg,
    float* __restrict__ out_exp)
{
    extern __shared__ float lds[];
    float* gys = lds;                        // [32 tok][128]  gelu(y) handoff

    const int tid  = threadIdx.x;
    const int wave = tid >> 6;
    const int lane = tid & 63;
    const int btok = blockIdx.x * TOK_PER_BLK;
    const int wtok = btok + wave * TT;       // this wave's first token

    float* gyw = gys + wave * TT * DIN;      // wave-private gy slice (4 KB)

    // ================= GEMM1: y[t][e][i] = x . w1 =================
    // lane -> (e = lane>>3, g = lane&7); computes i = 2g, 2g+1 for 8 tokens
    const int e1 = lane >> 3;
    const int g  = lane & 7;

    float y0[TT], y1[TT];
#pragma unroll
    for (int t = 0; t < TT; ++t) { y0[t] = 0.f; y1[t] = 0.f; }

    const float* xg = x + (size_t)wtok * DIN;     // wave-uniform base
    const float* Pl = P + lane * 8;

#pragma unroll 4
    for (int c4 = 0; c4 < DIN / 4; ++c4) {
        f32x4 wa = *(const f32x4*)(Pl + c4 * 512);
        f32x4 wb = *(const f32x4*)(Pl + c4 * 512 + 4);
#pragma unroll
        for (int t = 0; t < TT; ++t) {
            f32x4 xv = __builtin_nontemporal_load(
                (const f32x4*)(xg + t * DIN + c4 * 4));   // uniform addr, stream
            y0[t] += xv.x * wa.x + xv.y * wa.y + xv.z * wa.z + xv.w * wa.w;
            y1[t] += xv.x * wb.x + xv.y * wb.y + xv.z * wb.z + xv.w * wb.w;
        }
    }

    // ---- exact GELU, write to LDS handoff ----
#pragma unroll
    for (int t = 0; t < TT; ++t) {
        float a = y0[t], b = y1[t];
        a = 0.5f * a * (1.f + erff(a * 0.70710678118654752f));
        b = 0.5f * b * (1.f + erff(b * 0.70710678118654752f));
        *(float2*)(gyw + t * DIN + e1 * ISZ + 2 * g) = make_float2(a, b);
    }
    __syncthreads();

    // ================= GEMM2 + weighted agg =================
    // lane -> c4 = lane&31 (channel quad), h = lane>>5 (expert parity)
    const int c4 = lane & 31;
    const int h  = lane >> 5;

#pragma unroll
    for (int th = 0; th < 2; ++th) {          // two 4-token halves (reg pressure)
        float agg[4][4];
#pragma unroll
        for (int t = 0; t < 4; ++t) {
            agg[t][0] = 0.f; agg[t][1] = 0.f; agg[t][2] = 0.f; agg[t][3] = 0.f;
        }

#pragma unroll
        for (int k = 0; k < 4; ++k) {
            const int e = 2 * k + h;
            const float* w2e = w2 + e * (ISZ * DIN) + c4 * 4;
            float acc[4][4];
#pragma unroll
            for (int t = 0; t < 4; ++t) {
                acc[t][0] = 0.f; acc[t][1] = 0.f; acc[t][2] = 0.f; acc[t][3] = 0.f;
            }
#pragma unroll
            for (int i4 = 0; i4 < 4; ++i4) {
                f32x4 wv0 = *(const f32x4*)(w2e + (i4 * 4 + 0) * DIN);
                f32x4 wv1 = *(const f32x4*)(w2e + (i4 * 4 + 1) * DIN);
                f32x4 wv2 = *(const f32x4*)(w2e + (i4 * 4 + 2) * DIN);
                f32x4 wv3 = *(const f32x4*)(w2e + (i4 * 4 + 3) * DIN);
#pragma unroll
                for (int t = 0; t < 4; ++t) {
                    const int tt = th * 4 + t;
                    // broadcast LDS read (address depends only on h)
                    f32x4 gv = *(const f32x4*)(gyw + tt * DIN + e * ISZ + i4 * 4);
                    acc[t][0] += gv.x * wv0.x + gv.y * wv1.x + gv.z * wv2.x + gv.w * wv3.x;
                    acc[t][1] += gv.x * wv0.y + gv.y * wv1.y + gv.z * wv2.y + gv.w * wv3.y;
                    acc[t][2] += gv.x * wv0.z + gv.y * wv1.z + gv.z * wv2.z + gv.w * wv3.z;
                    acc[t][3] += gv.x * wv0.w + gv.y * wv1.w + gv.z * wv2.w + gv.w * wv3.w;
                }
            }
#pragma unroll
            for (int t = 0; t < 4; ++t) {
                const int gtok = wtok + th * 4 + t;
                f32x4 v = {acc[t][0], acc[t][1], acc[t][2], acc[t][3]};
                __builtin_nontemporal_store(v,
                    (f32x4*)(out_exp + (size_t)gtok * (NEXP * DIN) + e * DIN + c4 * 4));
                float r = rw[(size_t)gtok * NEXP + e];
                agg[t][0] += r * acc[t][0];
                agg[t][1] += r * acc[t][1];
                agg[t][2] += r * acc[t][2];
                agg[t][3] += r * acc[t][3];
            }
        }

        // combine expert parities: lane l (+) lane l^32, then lanes 0..31 write
#pragma unroll
        for (int t = 0; t < 4; ++t) {
#pragma unroll
            for (int j = 0; j < 4; ++j)
                agg[t][j] += __shfl_xor(agg[t][j], 32);
        }
        if (h == 0) {
#pragma unroll
            for (int t = 0; t < 4; ++t) {
                const int gtok = wtok + th * 4 + t;
                f32x4 v = {agg[t][0], agg[t][1], agg[t][2], agg[t][3]};
                __builtin_nontemporal_store(v,
                    (f32x4*)(out_agg + (size_t)gtok * DIN + c4 * 4));
            }
        }
    }
}

extern "C" void kernel_launch(void* const* d_in, const int* in_sizes, int n_in,
                              void* d_out, int out_size, void* d_ws, size_t ws_size,
                              hipStream_t stream) {
    const float* x  = (const float*)d_in[0];
    const float* rw = (const float*)d_in[1];
    const float* w1 = (const float*)d_in[2];
    const float* w2 = (const float*)d_in[3];

    float* out_agg = (float*)d_out;                  // [NTOK][128]
    float* out_exp = out_agg + (size_t)NTOK * DIN;   // [NTOK][8][128]
    float* P = (float*)d_ws;                         // 64 KB packed w1

    pack_w1_kernel<<<dim3(64), dim3(256), 0, stream>>>(w1, P);

    dim3 grid(NTOK / TOK_PER_BLK);   // 2048
    dim3 block(256);
    moe_fused_kernel<<<grid, block, SMEM_BYTES, stream>>>(
        x, rw, P, w2, out_agg, out_exp);
}

// Round 7
// 198.321 us; speedup vs baseline: 5.0915x; 1.0889x over previous
//
#include <hip/hip_runtime.h>
#include <math.h>

#define NEXP 8
#define DIN 128
#define ISZ 16
#define TT 8                       // tokens per wave (occupancy-friendly)
#define NWAVE 4
#define TOK_PER_BLK (TT * NWAVE)   // 32
#define NTOK (16 * 4096)           // 65536

#define LDS_GY (TOK_PER_BLK * DIN) // 4096 floats = 16 KB
#define SMEM_BYTES (LDS_GY * 4)

typedef float f32x4 __attribute__((ext_vector_type(4)));

// ---- pack w1 [e][c][i] into lane-major P: ----
// P[c4*512 + lane*8 + m*4 + k] = w1[e][4*c4+k][2*g+m],  lane = e*8+g
// GEMM1: lane (e,g) loads its 8 weights for c-chunk c4 as two contiguous
// float4s at P + c4*512 + lane*8 (each wave instruction covers 2 KB contiguous).
__global__ void pack_w1_kernel(const float* __restrict__ w1, float* __restrict__ P) {
    int idx = blockIdx.x * 256 + threadIdx.x;       // 0 .. 16383
    int c4 = idx >> 9;
    int r  = idx & 511;
    int ln = r >> 3;
    int j  = r & 7;
    int m  = j >> 2;
    int k  = j & 3;
    int e  = ln >> 3;
    int g  = ln & 7;
    P[idx] = w1[e * 2048 + (4 * c4 + k) * 16 + (2 * g + m)];
}

__global__ __launch_bounds__(256, 1) __attribute__((amdgpu_num_vgpr(128)))
void moe_fused_kernel(
    const float* __restrict__ x,
    const float* __restrict__ rw,
    const float* __restrict__ P,     // packed w1 in d_ws
    const float* __restrict__ w2,
    float* __restrict__ out_agg,
    float* __restrict__ out_exp)
{
    extern __shared__ float lds[];
    float* gys = lds;                        // [32 tok][128]  gelu(y) handoff

    const int tid  = threadIdx.x;
    const int wave = tid >> 6;
    const int lane = tid & 63;
    const int btok = blockIdx.x * TOK_PER_BLK;
    const int wtok = btok + wave * TT;       // this wave's first token

    float* gyw = gys + wave * TT * DIN;      // wave-private gy slice (4 KB)

    // ================= GEMM1: y[t][e][i] = x . w1 =================
    // lane -> (e = lane>>3, g = lane&7); computes i = 2g, 2g+1 for 8 tokens
    const int e1 = lane >> 3;
    const int g  = lane & 7;

    float y0[TT], y1[TT];
#pragma unroll
    for (int t = 0; t < TT; ++t) { y0[t] = 0.f; y1[t] = 0.f; }

    const float* xg = x + (size_t)wtok * DIN;     // wave-uniform base
    const float* Pl = P + lane * 8;

#pragma unroll 2
    for (int c4 = 0; c4 < DIN / 4; ++c4) {
        f32x4 wa = *(const f32x4*)(Pl + c4 * 512);
        f32x4 wb = *(const f32x4*)(Pl + c4 * 512 + 4);
#pragma unroll
        for (int t = 0; t < TT; ++t) {
            f32x4 xv = __builtin_nontemporal_load(
                (const f32x4*)(xg + t * DIN + c4 * 4));   // uniform addr, stream
            y0[t] += xv.x * wa.x + xv.y * wa.y + xv.z * wa.z + xv.w * wa.w;
            y1[t] += xv.x * wb.x + xv.y * wb.y + xv.z * wb.z + xv.w * wb.w;
        }
    }

    // ---- exact GELU, write to LDS handoff ----
#pragma unroll
    for (int t = 0; t < TT; ++t) {
        float a = y0[t], b = y1[t];
        a = 0.5f * a * (1.f + erff(a * 0.70710678118654752f));
        b = 0.5f * b * (1.f + erff(b * 0.70710678118654752f));
        *(float2*)(gyw + t * DIN + e1 * ISZ + 2 * g) = make_float2(a, b);
    }
    __syncthreads();

    // ================= GEMM2 + weighted agg =================
    // lane -> c4 = lane&31 (channel quad), h = lane>>5 (expert parity)
    const int c4 = lane & 31;
    const int h  = lane >> 5;

#pragma unroll
    for (int th = 0; th < 2; ++th) {          // two 4-token halves (reg pressure)
        float agg[4][4];
#pragma unroll
        for (int t = 0; t < 4; ++t) {
            agg[t][0] = 0.f; agg[t][1] = 0.f; agg[t][2] = 0.f; agg[t][3] = 0.f;
        }

#pragma unroll 1
        for (int k = 0; k < 4; ++k) {
            const int e = 2 * k + h;
            const float* w2e = w2 + e * (ISZ * DIN) + c4 * 4;
            float acc[4][4];
#pragma unroll
            for (int t = 0; t < 4; ++t) {
                acc[t][0] = 0.f; acc[t][1] = 0.f; acc[t][2] = 0.f; acc[t][3] = 0.f;
            }
#pragma unroll 2
            for (int i4 = 0; i4 < 4; ++i4) {
                f32x4 wv0 = *(const f32x4*)(w2e + (i4 * 4 + 0) * DIN);
                f32x4 wv1 = *(const f32x4*)(w2e + (i4 * 4 + 1) * DIN);
                f32x4 wv2 = *(const f32x4*)(w2e + (i4 * 4 + 2) * DIN);
                f32x4 wv3 = *(const f32x4*)(w2e + (i4 * 4 + 3) * DIN);
#pragma unroll
                for (int t = 0; t < 4; ++t) {
                    const int tt = th * 4 + t;
                    // broadcast LDS read (address depends only on h)
                    f32x4 gv = *(const f32x4*)(gyw + tt * DIN + e * ISZ + i4 * 4);
                    acc[t][0] += gv.x * wv0.x + gv.y * wv1.x + gv.z * wv2.x + gv.w * wv3.x;
                    acc[t][1] += gv.x * wv0.y + gv.y * wv1.y + gv.z * wv2.y + gv.w * wv3.y;
                    acc[t][2] += gv.x * wv0.z + gv.y * wv1.z + gv.z * wv2.z + gv.w * wv3.z;
                    acc[t][3] += gv.x * wv0.w + gv.y * wv1.w + gv.z * wv2.w + gv.w * wv3.w;
                }
            }
#pragma unroll
            for (int t = 0; t < 4; ++t) {
                const int gtok = wtok + th * 4 + t;
                f32x4 v = {acc[t][0], acc[t][1], acc[t][2], acc[t][3]};
                __builtin_nontemporal_store(v,
                    (f32x4*)(out_exp + (size_t)gtok * (NEXP * DIN) + e * DIN + c4 * 4));
                float r = rw[(size_t)gtok * NEXP + e];
                agg[t][0] += r * acc[t][0];
                agg[t][1] += r * acc[t][1];
                agg[t][2] += r * acc[t][2];
                agg[t][3] += r * acc[t][3];
            }
        }

        // combine expert parities: lane l (+) lane l^32, then lanes 0..31 write
#pragma unroll
        for (int t = 0; t < 4; ++t) {
#pragma unroll
            for (int j = 0; j < 4; ++j)
                agg[t][j] += __shfl_xor(agg[t][j], 32);
        }
        if (h == 0) {
#pragma unroll
            for (int t = 0; t < 4; ++t) {
                const int gtok = wtok + th * 4 + t;
                f32x4 v = {agg[t][0], agg[t][1], agg[t][2], agg[t][3]};
                __builtin_nontemporal_store(v,
                    (f32x4*)(out_agg + (size_t)gtok * DIN + c4 * 4));
            }
        }
    }
}

extern "C" void kernel_launch(void* const* d_in, const int* in_sizes, int n_in,
                              void* d_out, int out_size, void* d_ws, size_t ws_size,
                              hipStream_t stream) {
    const float* x  = (const float*)d_in[0];
    const float* rw = (const float*)d_in[1];
    const float* w1 = (const float*)d_in[2];
    const float* w2 = (const float*)d_in[3];

    float* out_agg = (float*)d_out;                  // [NTOK][128]
    float* out_exp = out_agg + (size_t)NTOK * DIN;   // [NTOK][8][128]
    float* P = (float*)d_ws;                         // 64 KB packed w1

    pack_w1_kernel<<<dim3(64), dim3(256), 0, stream>>>(w1, P);

    dim3 grid(NTOK / TOK_PER_BLK);   // 2048
    dim3 block(256);
    moe_fused_kernel<<<grid, block, SMEM_BYTES, stream>>>(
        x, rw, P, w2, out_agg, out_exp);
}

// Round 8
// 113.627 us; speedup vs baseline: 8.8866x; 1.7454x over previous
//
#include <hip/hip_runtime.h>
#include <math.h>

#define NEXP 8
#define DIN 128
#define ISZ 16
#define TT 8                       // tokens per wave
#define NWAVE 4
#define TOK_PER_BLK (TT * NWAVE)   // 32
#define NTOK (16 * 4096)           // 65536

#define LDS_X   (TOK_PER_BLK * DIN)   // 4096 floats
#define LDS_GY  (TOK_PER_BLK * DIN)   // 4096 floats
#define LDS_RW  (TOK_PER_BLK * NEXP)  // 256 floats
#define SMEM_BYTES ((LDS_X + LDS_GY + LDS_RW) * 4)   // 33 KB

typedef float f32x4 __attribute__((ext_vector_type(4)));

// ---- pack w1 [e][c][i] into lane-major P ----
// P[c4*512 + lane*8 + m*4 + k] = w1[e][4*c4+k][2*g+m],  lane = e*8+g
__global__ void pack_w1_kernel(const float* __restrict__ w1, float* __restrict__ P) {
    int idx = blockIdx.x * 256 + threadIdx.x;       // 0 .. 16383
    int c4 = idx >> 9;
    int r  = idx & 511;
    int ln = r >> 3;
    int j  = r & 7;
    int m  = j >> 2;
    int k  = j & 3;
    int e  = ln >> 3;
    int g  = ln & 7;
    P[idx] = w1[e * 2048 + (4 * c4 + k) * 16 + (2 * g + m)];
}

__global__ __launch_bounds__(256, 1) __attribute__((amdgpu_num_vgpr(128)))
void moe_fused_kernel(
    const float* __restrict__ x,
    const float* __restrict__ rw,
    const float* __restrict__ P,     // packed w1 in d_ws
    const float* __restrict__ w2,
    float* __restrict__ out_agg,
    float* __restrict__ out_exp)
{
    extern __shared__ float lds[];
    float* xs  = lds;                 // [32 tok][128] staged x
    float* gys = xs + LDS_X;          // [32 tok][128] gelu(y), wave-private slices
    float* rws = gys + LDS_GY;        // [32 tok][8]   routing weights

    const int tid  = threadIdx.x;
    const int wave = tid >> 6;
    const int lane = tid & 63;
    const int btok = blockIdx.x * TOK_PER_BLK;
    const int wtok = btok + wave * TT;

    // ---- cooperative stage: x tile (16 KB) + routing (1 KB) ----
    {
        const f32x4* src = (const f32x4*)(x + (size_t)btok * DIN);
        f32x4* dst = (f32x4*)xs;
#pragma unroll
        for (int i = 0; i < 4; ++i)
            dst[tid + 256 * i] = src[tid + 256 * i];
        rws[tid] = rw[(size_t)btok * NEXP + tid];
    }
    __syncthreads();

    const float* xw = xs + wave * TT * DIN;
    float* gyw = gys + wave * TT * DIN;

    // ================= GEMM1: y[t][e][i] = x . w1 =================
    // lane -> (e1 = lane>>3, g = lane&7); computes i = 2g, 2g+1 for 8 tokens
    const int e1 = lane >> 3;
    const int g  = lane & 7;

    float y0[TT], y1[TT];
#pragma unroll
    for (int t = 0; t < TT; ++t) { y0[t] = 0.f; y1[t] = 0.f; }

    const float* Pl = P + lane * 8;
    // software pipeline: a0/b0 = weights for c4, a1/b1 for c4+1, prefetch +2
    f32x4 a0 = *(const f32x4*)(Pl + 0);
    f32x4 b0 = *(const f32x4*)(Pl + 4);
    f32x4 a1 = *(const f32x4*)(Pl + 512);
    f32x4 b1 = *(const f32x4*)(Pl + 516);

#pragma unroll 1
    for (int c4 = 0; c4 < 32; c4 += 2) {
        const int p = (c4 + 2 < 32) ? c4 + 2 : 30;   // clamped prefetch
        f32x4 a2 = *(const f32x4*)(Pl + p * 512);
        f32x4 b2 = *(const f32x4*)(Pl + p * 512 + 4);
        f32x4 a3 = *(const f32x4*)(Pl + (p + 1) * 512);
        f32x4 b3 = *(const f32x4*)(Pl + (p + 1) * 512 + 4);
#pragma unroll
        for (int t = 0; t < TT; ++t) {
            f32x4 x0 = *(const f32x4*)(xw + t * DIN + c4 * 4);       // broadcast
            f32x4 x1 = *(const f32x4*)(xw + t * DIN + c4 * 4 + 4);   // broadcast
            y0[t] += x0.x * a0.x + x0.y * a0.y + x0.z * a0.z + x0.w * a0.w
                   + x1.x * a1.x + x1.y * a1.y + x1.z * a1.z + x1.w * a1.w;
            y1[t] += x0.x * b0.x + x0.y * b0.y + x0.z * b0.z + x0.w * b0.w
                   + x1.x * b1.x + x1.y * b1.y + x1.z * b1.z + x1.w * b1.w;
        }
        a0 = a2; b0 = b2; a1 = a3; b1 = b3;
    }

    // ---- exact GELU -> wave-private LDS slice (no barrier needed) ----
#pragma unroll
    for (int t = 0; t < TT; ++t) {
        float a = y0[t], b = y1[t];
        a = 0.5f * a * (1.f + erff(a * 0.70710678118654752f));
        b = 0.5f * b * (1.f + erff(b * 0.70710678118654752f));
        *(float2*)(gyw + t * DIN + e1 * ISZ + 2 * g) = make_float2(a, b);
    }
    // gy is produced and consumed by the SAME wave -> no __syncthreads here.

    // ================= GEMM2 + weighted agg =================
    // lane -> c4s = (lane&31)*4 channel quad, h = lane>>5 expert parity
    const int c4s = (lane & 31) * 4;
    const int h   = lane >> 5;
    const float* w2h = w2 + h * (ISZ * DIN) + c4s;  // expert e=2k+h -> + k*4096
    const f32x4 vzero = (f32x4)(0.f);

#pragma unroll
    for (int th = 0; th < 2; ++th) {          // two 4-token halves
        f32x4 acc[4], agg[4];
#pragma unroll
        for (int t = 0; t < 4; ++t) { acc[t] = vzero; agg[t] = vzero; }

        // prime chunk 0 (k=0, i4=0): rows 0..3 of expert h
        f32x4 w0 = *(const f32x4*)(w2h + 0);
        f32x4 wv1 = *(const f32x4*)(w2h + 128);
        f32x4 wv2 = *(const f32x4*)(w2h + 256);
        f32x4 wv3 = *(const f32x4*)(w2h + 384);

#pragma unroll 1
        for (int ch = 0; ch < 16; ++ch) {     // (k = ch>>2, i4 = ch&3)
            const int k  = ch >> 2;
            const int i4 = ch & 3;
            const int nch = (ch < 15) ? ch + 1 : 15;   // clamped prefetch
            const float* nb = w2h + (nch >> 2) * 4096 + (nch & 3) * 4 * DIN;
            f32x4 n0 = *(const f32x4*)(nb + 0);
            f32x4 n1 = *(const f32x4*)(nb + 128);
            f32x4 n2 = *(const f32x4*)(nb + 256);
            f32x4 n3 = *(const f32x4*)(nb + 384);

            const int e = 2 * k + h;
#pragma unroll
            for (int t = 0; t < 4; ++t) {
                f32x4 gv = *(const f32x4*)(gyw + (th * 4 + t) * DIN + e * ISZ + i4 * 4);
                acc[t] += w0 * gv.x + wv1 * gv.y + wv2 * gv.z + wv3 * gv.w;
            }

            if (i4 == 3) {   // expert e complete: store + weighted agg + reset
#pragma unroll
                for (int t = 0; t < 4; ++t) {
                    const int gtok = wtok + th * 4 + t;
                    __builtin_nontemporal_store(acc[t],
                        (f32x4*)(out_exp + (size_t)gtok * (NEXP * DIN) + e * DIN + c4s));
                    float r = rws[(wave * TT + th * 4 + t) * NEXP + e];
                    agg[t] += r * acc[t];
                    acc[t] = vzero;
                }
            }
            w0 = n0; wv1 = n1; wv2 = n2; wv3 = n3;
        }

        // combine expert parities: lane l (+) lane l^32, then lanes 0..31 write
#pragma unroll
        for (int t = 0; t < 4; ++t) {
            agg[t].x += __shfl_xor(agg[t].x, 32);
            agg[t].y += __shfl_xor(agg[t].y, 32);
            agg[t].z += __shfl_xor(agg[t].z, 32);
            agg[t].w += __shfl_xor(agg[t].w, 32);
        }
        if (h == 0) {
#pragma unroll
            for (int t = 0; t < 4; ++t) {
                const int gtok = wtok + th * 4 + t;
                __builtin_nontemporal_store(agg[t],
                    (f32x4*)(out_agg + (size_t)gtok * DIN + c4s));
            }
        }
    }
}

extern "C" void kernel_launch(void* const* d_in, const int* in_sizes, int n_in,
                              void* d_out, int out_size, void* d_ws, size_t ws_size,
                              hipStream_t stream) {
    const float* x  = (const float*)d_in[0];
    const float* rw = (const float*)d_in[1];
    const float* w1 = (const float*)d_in[2];
    const float* w2 = (const float*)d_in[3];

    float* out_agg = (float*)d_out;                  // [NTOK][128]
    float* out_exp = out_agg + (size_t)NTOK * DIN;   // [NTOK][8][128]
    float* P = (float*)d_ws;                         // 64 KB packed w1

    pack_w1_kernel<<<dim3(64), dim3(256), 0, stream>>>(w1, P);

    dim3 grid(NTOK / TOK_PER_BLK);   // 2048
    dim3 block(256);
    moe_fused_kernel<<<grid, block, SMEM_BYTES, stream>>>(
        x, rw, P, w2, out_agg, out_exp);
}